// Round 7
// baseline (3443.819 us; speedup 1.0000x reference)
//
#include <hip/hip_runtime.h>
#include <math.h>

#define T_LEN 512
#define AGT __HIP_MEMORY_SCOPE_AGENT
#define SPIN_MAX 65536   // hang-proofing: legit skew <=~10us; this is ~15-30ms
typedef unsigned long long u64;

// LDS-only barrier: every intra-block handoff in the scan goes through LDS,
// so drain lgkmcnt ONLY. Publish stores (mailbox u64 atomics) and the
// hidden[] global stores ride across barriers and complete asynchronously;
// poll loads force their own vmcnt wait at first use (data dependency).
// rule #18: sched_barrier(0) pins ordering after the inline-asm wait.
#define SYNCL() do { \
    asm volatile("s_waitcnt lgkmcnt(0)" ::: "memory"); \
    __builtin_amdgcn_s_barrier(); \
    __builtin_amdgcn_sched_barrier(0); \
} while (0)

// ---------------- workspace layout (bytes) ----------------
// 0x0100 : u64 nullw[5]  stride 32 u64 (256 B)   tagged (tag<<32|bits) null_attn
// 0x0800 : u64 kcg[2][5][32]   (par, mech, DC)   tagged kc (selected variant)
// 0x1800 : u64 vcg[2][5][128]  tagged vc (selected variant)
// 0x4000 : float keys[512*6*64]
// 0x4000+0xC0000 : float vals[512*6*64]
// 0x4000+2*0xC0000 : float hidden[512*640]

__device__ __forceinline__ float tanh_f(float x) {
    const float e = __expf(2.f * x);
    return 1.f - 2.f / (e + 1.f);
}

// ============ kernel 1: key/value projections (parallel) ============
__global__ __launch_bounds__(128) void precompute_kv(
    const float* __restrict__ bert, const int* __restrict__ uidx, const int* __restrict__ pidx,
    const float* __restrict__ disg, const float* __restrict__ udisg,
    const float* __restrict__ utab, const float* __restrict__ ptab,
    const float* __restrict__ Wk0, const float* __restrict__ Wv0,
    const float* __restrict__ Wk1, const float* __restrict__ Wv1,
    const float* __restrict__ Wk2, const float* __restrict__ Wv2,
    const float* __restrict__ Wk3, const float* __restrict__ Wv3,
    const float* __restrict__ Wk4, const float* __restrict__ Wv4,
    float* __restrict__ keys, float* __restrict__ vals)
{
    __shared__ float x[768 + 50 + 20 + 2 + 2];
    const int t = blockIdx.x, tid = threadIdx.x;
    for (int i = tid; i < 768; i += 128) x[i] = bert[t * 768 + i];
    const int u = uidx[t], p = pidx[t];
    for (int i = tid; i < 50; i += 128) x[768 + i] = utab[u * 50 + i];
    for (int i = tid; i < 20; i += 128) x[818 + i] = ptab[p * 20 + i];
    if (tid < 2) x[838 + tid] = disg[t * 2 + tid];
    if (tid >= 2 && tid < 4) x[840 + (tid - 2)] = udisg[t * 2 + (tid - 2)];
    __syncthreads();
    const int j = tid & 63, isv = tid >> 6;
    float* outb = (isv ? vals : keys) + t * 384;
    {   const float* W = isv ? Wv0 : Wk0; float a = 0.f;
        for (int i = 0; i < 768; ++i) a += x[i] * W[i * 64 + j];
        outb[0 * 64 + j] = a; }
    {   const float* W = isv ? Wv1 : Wk1; float a = 0.f;
        for (int i = 0; i < 50; ++i) a += x[768 + i] * W[i * 64 + j];
        outb[1 * 64 + j] = a; }
    {   const float* W = isv ? Wv2 : Wk2; float a = 0.f;
        for (int i = 0; i < 20; ++i) a += x[818 + i] * W[i * 64 + j];
        outb[2 * 64 + j] = a; }
    {   const float* W = isv ? Wv3 : Wk3;
        outb[3 * 64 + j] = x[838] * W[j] + x[839] * W[64 + j]; }
    {   const float* W = isv ? Wv4 : Wk4;
        outb[4 * 64 + j] = x[840] * W[j] + x[841] * W[64 + j]; }
    outb[5 * 64 + j] = 0.f;   // null key/value row
}

// ============ kernel 2: the sequential RIM scan ============
// R2/R6 schedule (3092 us anchor). This round's single concept: keep EVERY
// vmem wait off the critical path.
//  - ALL in-loop barriers are LDS-only (all intra-block handoffs are LDS:
//    sqp/sop/shn/snull/qcl/kcl/vcl/slog/skey/sval; hidden[] is inter-kernel).
//  - Poll loads are ISSUE-EARLY / CHECK-LATE: null polls issue before the
//    gate matvec (flight hides under ~400cy of FMA); kc/vc polls issue at
//    S3-end so their first flight overlaps SYNC4 + publisher skew.
// Transport: agent-scope relaxed u64 atomics (tag travels with data).
// All spins bounded (SPIN_MAX): visibility failure -> wrong answer, not hang.

#define SMEM_FLOATS 35216

__global__ void __attribute__((amdgpu_flat_work_group_size(512, 512), amdgpu_waves_per_eu(2, 2)))
rim_scan(
    const float* __restrict__ Wq, const float* __restrict__ Wih, const float* __restrict__ Whh,
    const float* __restrict__ b_lstm, const float* __restrict__ Wqc, const float* __restrict__ Wkc,
    const float* __restrict__ Wvc,
    const float* __restrict__ keys, const float* __restrict__ vals,
    float* __restrict__ hidden,
    u64* __restrict__ nullw, u64* __restrict__ kcg, u64* __restrict__ vcg)
{
    if (blockIdx.x & 7) return;                 // XCD-pinning dummies
    const int mech = blockIdx.x >> 3;

    extern __shared__ float sm[];
    float* swq  = sm;            // 8192  Wq_T  [64 out][128 K] swizzled
    float* swqc = sm + 8192;     // 4096  Wqc_T [32][128]
    float* swkc = sm + 12288;    // 4096  Wkc_T [32][128]
    float* swvc = sm + 16384;    // 16384 Wvc_T [128][128]
    float* skey = sm + 32768;    // 2*384 key double-buffer
    float* sval = sm + 33536;    // 2*384 val double-buffer
    float* sqp  = sm + 34304;    // 256   q partials (4 segs x 64)
    float* sh   = sm + 34560;    // 128   h state
    float* shn  = sm + 34688;    // 128   h_new candidate
    float* sop  = sm + 34816;    // 192   gate operand: [inp(64) | h(128)]
    float* qcl  = sm + 35008;    // 32    qc (selected variant)
    float* kcl  = sm + 35040;    // 32    kc
    float* vcl  = sm + 35072;    // 128   vc
    float* slog = sm + 35200;    // 8     ctx logits
    float* snull= sm + 35208;    // 8

    const int tid = threadIdx.x;
    const int lane = tid & 63, wv = tid >> 6;

    // ---- stage transposed+swizzled weights into LDS
    for (int idx = tid; idx < 8192; idx += 512) {
        const int i = idx >> 6, j = idx & 63;
        swq[j * 128 + ((((i >> 2) ^ (j & 7)) << 2) | (i & 3))] = Wq[mech * 8192 + idx];
    }
    for (int idx = tid; idx < 4096; idx += 512) {
        const int i = idx >> 5, c = idx & 31;
        const int pos = c * 128 + ((((i >> 2) ^ (c & 7)) << 2) | (i & 3));
        swqc[pos] = Wqc[mech * 4096 + idx];
        swkc[pos] = Wkc[mech * 4096 + idx];
    }
    for (int idx = tid; idx < 16384; idx += 512) {
        const int i = idx >> 7, o = idx & 127;
        swvc[o * 128 + ((((i >> 2) ^ (o & 7)) << 2) | (i & 3))] = Wvc[mech * 16384 + idx];
    }
    if (tid < 384) { skey[tid] = keys[tid]; sval[tid] = vals[tid]; }  // prime t=0
    if (tid < 192) sop[tid] = 0.f;
    if (tid < 128) { sh[tid] = 0.f; shn[tid] = 0.f; }

    // ---- gate weights in registers. quad j covers cell j's 4 gates:
    // pair even -> (i_j, g_j), pair odd -> (f_j, o_j); s = K-half.
    const int pair = tid >> 1, s = tid & 1;
    const int o0 = (pair >> 1) + (pair & 1) * 128;   // i_j or f_j
    const int o1 = o0 + 256;                          // g_j or o_j
    float wA[96], wB[96];
    if (s == 0) {
        #pragma unroll
        for (int k = 0; k < 64; ++k) {
            wA[k] = Wih[mech * 32768 + k * 512 + o0];
            wB[k] = Wih[mech * 32768 + k * 512 + o1];
        }
        #pragma unroll
        for (int k = 0; k < 32; ++k) {
            wA[64 + k] = Whh[mech * 65536 + k * 512 + o0];
            wB[64 + k] = Whh[mech * 65536 + k * 512 + o1];
        }
    } else {
        #pragma unroll
        for (int k = 0; k < 96; ++k) {
            wA[k] = Whh[mech * 65536 + (32 + k) * 512 + o0];
            wB[k] = Whh[mech * 65536 + (32 + k) * 512 + o1];
        }
    }
    const float b0v = (s == 0) ? b_lstm[mech * 512 + o0] : 0.f;
    const float b1v = (s == 0) ? b_lstm[mech * 512 + o1] : 0.f;
    float c_reg = 0.f, cn = 0.f;
    __syncthreads();   // one full drain before the scan

    #pragma unroll 1
    for (int t = 0; t < T_LEN; ++t) {
        const int par = t & 1;
        const unsigned tgt = (unsigned)(t + 1);
        const float* kb = skey + par * 384;
        const float* vb = sval + par * 384;

        // one-wave 32-out matvec (2 lanes/out), optional tagged publish
        auto qk32 = [&](const float* Wl, const float* hsrc, float* dstL, u64* gbase) {
            const int out = lane >> 1, s2 = lane & 1, rx = out & 7;
            const float* wrow = Wl + out * 128;
            const float4* h4 = (const float4*)(hsrc + s2 * 64);
            float p = 0.f;
            #pragma unroll
            for (int j = 0; j < 16; ++j) {
                const float4 w = *(const float4*)(wrow + (((s2 * 16 + j) ^ rx) << 2));
                const float4 hv = h4[j];
                p += w.x * hv.x + w.y * hv.y + w.z * hv.z + w.w * hv.w;
            }
            p += __shfl_xor(p, 1);
            if (s2 == 0) {
                dstL[out] = p;
                if (gbase)
                    __hip_atomic_store(gbase + out,
                                       ((u64)tgt << 32) | (u64)__float_as_uint(p),
                                       __ATOMIC_RELAXED, AGT);
            }
        };
        // four-wave 128-out vc matvec (2 lanes/out), tagged publish
        auto vc128 = [&](const float* hsrc, int wbase) {
            const int out = (wv - wbase) * 32 + (lane >> 1), s2 = lane & 1, rx = out & 7;
            const float* wrow = swvc + out * 128;
            const float4* h4 = (const float4*)(hsrc + s2 * 64);
            float p = 0.f;
            #pragma unroll
            for (int j = 0; j < 16; ++j) {
                const float4 w = *(const float4*)(wrow + (((s2 * 16 + j) ^ rx) << 2));
                const float4 hv = h4[j];
                p += w.x * hv.x + w.y * hv.y + w.z * hv.z + w.w * hv.w;
            }
            p += __shfl_xor(p, 1);
            if (s2 == 0) {
                vcl[out] = p;
                __hip_atomic_store(vcg + (((par * 5 + mech) << 7) + out),
                                   ((u64)tgt << 32) | (u64)__float_as_uint(p),
                                   __ATOMIC_RELAXED, AGT);
            }
        };

        // ================= S0: q partials =================
        if (wv < 4) {
            const int out = lane, rx = out & 7;
            const float* wrow = swq + out * 128;
            const float4* h4 = (const float4*)(sh + wv * 32);
            float acc = 0.f;
            #pragma unroll
            for (int j = 0; j < 8; ++j) {
                const float4 w = *(const float4*)(wrow + (((wv * 8 + j) ^ rx) << 2));
                const float4 hv = h4[j];
                acc += w.x * hv.x + w.y * hv.y + w.z * hv.z + w.w * hv.w;
            }
            sqp[wv * 64 + out] = acc;
        }
        SYNCL();   // SYNC1

        // ================= S1: attention + tagged null publish =================
        if (wv == 0) {
            const float q = sqp[lane] + sqp[64 + lane] + sqp[128 + lane] + sqp[192 + lane];
            float l[6];
            #pragma unroll
            for (int k = 0; k < 6; ++k) {
                float p = q * kb[k * 64 + lane];
                p += __shfl_down(p, 32); p += __shfl_down(p, 16); p += __shfl_down(p, 8);
                p += __shfl_down(p, 4);  p += __shfl_down(p, 2);  p += __shfl_down(p, 1);
                l[k] = __shfl(p, 0) * 0.125f;
            }
            const float mx = fmaxf(fmaxf(fmaxf(l[0], l[1]), fmaxf(l[2], l[3])), fmaxf(l[4], l[5]));
            const float e0 = __expf(l[0] - mx), e1 = __expf(l[1] - mx), e2 = __expf(l[2] - mx);
            const float e3 = __expf(l[3] - mx), e4 = __expf(l[4] - mx), e5 = __expf(l[5] - mx);
            const float inv = 1.f / (e0 + e1 + e2 + e3 + e4 + e5);
            sop[lane] = (e0 * vb[lane] + e1 * vb[64 + lane] + e2 * vb[128 + lane]
                       + e3 * vb[192 + lane] + e4 * vb[256 + lane] + e5 * vb[320 + lane]) * inv;
            if (lane == 0) {
                const float nv = e5 * inv;
                snull[mech] = nv;
                __hip_atomic_store(nullw + (mech << 5),
                                   ((u64)tgt << 32) | (u64)__float_as_uint(nv),
                                   __ATOMIC_RELAXED, AGT);
            }
        }
        SYNCL();   // SYNC2

        // ====== S2: issue null polls EARLY, gates+LSTM, then check polls ======
        const u64* np = (tid < 5 && tid != mech) ? (nullw + (tid << 5)) : (const u64*)0;
        u64 nw = 0;
        if (np) nw = __hip_atomic_load(np, __ATOMIC_RELAXED, AGT);   // flight hides under gates
        {
            const float4* op = (const float4*)(sop + s * 96);
            float p0 = b0v, p1 = b1v;
            #pragma unroll
            for (int q = 0; q < 24; ++q) {
                const float4 v = op[q];
                p0 += v.x * wA[4 * q] + v.y * wA[4 * q + 1] + v.z * wA[4 * q + 2] + v.w * wA[4 * q + 3];
                p1 += v.x * wB[4 * q] + v.y * wB[4 * q + 1] + v.z * wB[4 * q + 2] + v.w * wB[4 * q + 3];
            }
            const float r0 = p0 + __shfl_xor(p0, 1);
            const float r1 = p1 + __shfl_xor(p1, 1);
            const float t0 = __shfl_xor(r0, 2);
            const float t1 = __shfl_xor(r1, 2);
            const bool even = ((pair & 1) == 0);
            const float gi = even ? r0 : t0;
            const float gg = even ? r1 : t1;
            const float gf = even ? t0 : r0;
            const float go = even ? t1 : r1;
            const float si = 1.f / (1.f + __expf(-gi));
            const float sf = 1.f / (1.f + __expf(-gf));
            const float so = 1.f / (1.f + __expf(-go));
            cn = sf * c_reg + si * tanh_f(gg);
            const float hn = so * tanh_f(cn);
            if ((tid & 3) == 0) shn[tid >> 2] = hn;
        }
        if (np) {
            int spin = 0;
            while ((unsigned)(nw >> 32) < tgt && ++spin < SPIN_MAX)
                nw = __hip_atomic_load(np, __ATOMIC_RELAXED, AGT);
            snull[tid] = __uint_as_float((unsigned)nw);
        }
        SYNCL();   // SYNC3

        // ================= S3: selection + single-variant matvecs =================
        int selfAct;
        {
            const float myn = snull[mech]; int r = 0;
            #pragma unroll
            for (int mm = 0; mm < 5; ++mm) {
                const float o = snull[mm];
                r += (o < myn || (o == myn && mm < mech)) ? 1 : 0;
            }
            selfAct = (r < 3) ? 1 : 0;
        }
        c_reg = selfAct ? cn : c_reg;
        {
            const float* hsrc = selfAct ? shn : sh;
            if (wv == 0)      qk32(swqc, hsrc, qcl, (u64*)0);
            else if (wv == 1) qk32(swkc, hsrc, kcl, kcg + ((par * 5 + mech) << 5));
            else if (wv >= 2 && wv <= 5) vc128(hsrc, 2);
            else if (wv == 6) {
                const int tn = (t < T_LEN - 1) ? t + 1 : t;
                const float4* kn = (const float4*)(keys + tn * 384);
                float4* kd = (float4*)(skey + ((t + 1) & 1) * 384);
                kd[lane] = kn[lane];
                if (lane < 32) kd[64 + lane] = kn[64 + lane];
            } else {
                const int tn = (t < T_LEN - 1) ? t + 1 : t;
                const float4* vn = (const float4*)(vals + tn * 384);
                float4* vd = (float4*)(sval + ((t + 1) & 1) * 384);
                vd[lane] = vn[lane];
                if (lane < 32) vd[64 + lane] = vn[64 + lane];
            }
        }
        // ---- issue-early S5 poll loads: flight overlaps SYNC4 + remote skew
        const u64* kp = (const u64*)0;
        u64 pk = 0;
        if (wv >= 3 && lane < 32) {
            const int m2 = wv - 3;
            if (m2 != mech) {
                kp = kcg + (((par * 5 + m2) << 5) + lane);
                pk = __hip_atomic_load(kp, __ATOMIC_RELAXED, AGT);
            }
        }
        const u64* vb0 = vcg + tid;   // valid arithmetic; deref only if tid<128
        u64 pa0 = 0, pa1 = 0, pa2 = 0, pa3 = 0, pa4 = 0;
        if (tid < 128) {
            if (mech != 0) pa0 = __hip_atomic_load(vb0 + ((par * 5 + 0) << 7), __ATOMIC_RELAXED, AGT);
            if (mech != 1) pa1 = __hip_atomic_load(vb0 + ((par * 5 + 1) << 7), __ATOMIC_RELAXED, AGT);
            if (mech != 2) pa2 = __hip_atomic_load(vb0 + ((par * 5 + 2) << 7), __ATOMIC_RELAXED, AGT);
            if (mech != 3) pa3 = __hip_atomic_load(vb0 + ((par * 5 + 3) << 7), __ATOMIC_RELAXED, AGT);
            if (mech != 4) pa4 = __hip_atomic_load(vb0 + ((par * 5 + 4) << 7), __ATOMIC_RELAXED, AGT);
        }
        SYNCL();   // SYNC4

        // ================= S5: check polls + ctx logits =================
        float v0 = 0.f, v1 = 0.f, v2 = 0.f, v3 = 0.f, v4 = 0.f;
        if (wv >= 3 && lane < 32) {
            const int m2 = wv - 3;
            float kcv;
            if (m2 == mech) kcv = kcl[lane];
            else {
                int spin = 0;
                while ((unsigned)(pk >> 32) < tgt && ++spin < SPIN_MAX)
                    pk = __hip_atomic_load(kp, __ATOMIC_RELAXED, AGT);
                kcv = __uint_as_float((unsigned)pk);
            }
            float p = qcl[lane] * kcv;
            p += __shfl_down(p, 16); p += __shfl_down(p, 8); p += __shfl_down(p, 4);
            p += __shfl_down(p, 2);  p += __shfl_down(p, 1);
            if (lane == 0) slog[m2] = p * 0.17677669529663687f;
        }
        if (tid < 128) {
            int spin = 0;
            if (mech != 0) while ((unsigned)(pa0 >> 32) < tgt && ++spin < SPIN_MAX)
                pa0 = __hip_atomic_load(vb0 + ((par * 5 + 0) << 7), __ATOMIC_RELAXED, AGT);
            if (mech != 1) while ((unsigned)(pa1 >> 32) < tgt && ++spin < SPIN_MAX)
                pa1 = __hip_atomic_load(vb0 + ((par * 5 + 1) << 7), __ATOMIC_RELAXED, AGT);
            if (mech != 2) while ((unsigned)(pa2 >> 32) < tgt && ++spin < SPIN_MAX)
                pa2 = __hip_atomic_load(vb0 + ((par * 5 + 2) << 7), __ATOMIC_RELAXED, AGT);
            if (mech != 3) while ((unsigned)(pa3 >> 32) < tgt && ++spin < SPIN_MAX)
                pa3 = __hip_atomic_load(vb0 + ((par * 5 + 3) << 7), __ATOMIC_RELAXED, AGT);
            if (mech != 4) while ((unsigned)(pa4 >> 32) < tgt && ++spin < SPIN_MAX)
                pa4 = __hip_atomic_load(vb0 + ((par * 5 + 4) << 7), __ATOMIC_RELAXED, AGT);
            v0 = (mech == 0) ? vcl[tid] : __uint_as_float((unsigned)pa0);
            v1 = (mech == 1) ? vcl[tid] : __uint_as_float((unsigned)pa1);
            v2 = (mech == 2) ? vcl[tid] : __uint_as_float((unsigned)pa2);
            v3 = (mech == 3) ? vcl[tid] : __uint_as_float((unsigned)pa3);
            v4 = (mech == 4) ? vcl[tid] : __uint_as_float((unsigned)pa4);
        }
        SYNCL();   // SYNC5

        // ================= S6: ctx softmax + h2 + store =================
        if (tid < 128) {
            const float l0 = slog[0], l1 = slog[1], l2 = slog[2], l3 = slog[3], l4 = slog[4];
            const float mx = fmaxf(fmaxf(fmaxf(l0, l1), fmaxf(l2, l3)), l4);
            const float e0 = __expf(l0 - mx), e1 = __expf(l1 - mx), e2 = __expf(l2 - mx);
            const float e3 = __expf(l3 - mx), e4 = __expf(l4 - mx);
            const float inv = 1.f / (e0 + e1 + e2 + e3 + e4);
            float hv = selfAct ? shn[tid] : sh[tid];
            if (selfAct) hv += (e0 * v0 + e1 * v1 + e2 * v2 + e3 * v3 + e4 * v4) * inv;
            sh[tid] = hv;
            sop[64 + tid] = hv;
            hidden[t * 640 + mech * 128 + tid] = hv;   // ack rides (inter-kernel reader)
        }
        SYNCL();   // SYNC6
    }
}

// ============ kernel 3: classifier ============
__global__ __launch_bounds__(256) void cls_kernel(
    const float* __restrict__ hidden, const float* __restrict__ Wcls,
    const float* __restrict__ bcls, float* __restrict__ out)
{
    const int t = blockIdx.x * 256 + threadIdx.x;
    if (t >= T_LEN) return;
    float a0 = bcls[0], a1 = bcls[1];
    for (int d = 0; d < 640; ++d) {
        const float h = hidden[t * 640 + d];
        a0 += h * Wcls[d * 2 + 0];
        a1 += h * Wcls[d * 2 + 1];
    }
    out[t * 2 + 0] = a0;
    out[t * 2 + 1] = a1;
}

extern "C" void kernel_launch(void* const* d_in, const int* in_sizes, int n_in,
                              void* d_out, int out_size, void* d_ws, size_t ws_size,
                              hipStream_t stream)
{
    (void)in_sizes; (void)n_in; (void)out_size; (void)ws_size;
    const float* bert  = (const float*)d_in[0];
    const int*   uidx  = (const int*)d_in[1];
    const int*   pidx  = (const int*)d_in[2];
    const float* disg  = (const float*)d_in[3];
    const float* udisg = (const float*)d_in[4];
    const float* utab  = (const float*)d_in[5];
    const float* ptab  = (const float*)d_in[6];
    const float* Wk0 = (const float*)d_in[7],  *Wv0 = (const float*)d_in[8];
    const float* Wk1 = (const float*)d_in[9],  *Wv1 = (const float*)d_in[10];
    const float* Wk2 = (const float*)d_in[11], *Wv2 = (const float*)d_in[12];
    const float* Wk3 = (const float*)d_in[13], *Wv3 = (const float*)d_in[14];
    const float* Wk4 = (const float*)d_in[15], *Wv4 = (const float*)d_in[16];
    const float* Wq   = (const float*)d_in[17];
    const float* Wih  = (const float*)d_in[18];
    const float* Whh  = (const float*)d_in[19];
    const float* bl   = (const float*)d_in[20];
    const float* Wqc  = (const float*)d_in[21];
    const float* Wkc  = (const float*)d_in[22];
    const float* Wvc  = (const float*)d_in[23];
    const float* Wcls = (const float*)d_in[24];
    const float* bcls = (const float*)d_in[25];

    char* ws = (char*)d_ws;
    u64* nullw = (u64*)(ws + 0x100);    // stride 32 u64 = 256 B per mech
    u64* kcg   = (u64*)(ws + 0x800);
    u64* vcg   = (u64*)(ws + 0x1800);
    float* keys   = (float*)(ws + 0x4000);
    float* vals   = (float*)(ws + 0x4000 + 786432);
    float* hidden = (float*)(ws + 0x4000 + 2 * 786432);

    hipMemsetAsync(d_ws, 0, 0x4000, stream);   // zero all mailbox tags

    hipLaunchKernelGGL(precompute_kv, dim3(T_LEN), dim3(128), 0, stream,
        bert, uidx, pidx, disg, udisg, utab, ptab,
        Wk0, Wv0, Wk1, Wv1, Wk2, Wv2, Wk3, Wv3, Wk4, Wv4, keys, vals);

    const int smem_bytes = SMEM_FLOATS * 4;   // 140864 B < 160 KiB
    (void)hipFuncSetAttribute((const void*)rim_scan,
                              hipFuncAttributeMaxDynamicSharedMemorySize, smem_bytes);
    hipLaunchKernelGGL(rim_scan, dim3(33), dim3(512), smem_bytes, stream,
        Wq, Wih, Whh, bl, Wqc, Wkc, Wvc, keys, vals, hidden, nullw, kcg, vcg);

    hipLaunchKernelGGL(cls_kernel, dim3(2), dim3(256), 0, stream,
        hidden, Wcls, bcls, (float*)d_out);
}

// Round 8
// 3275.073 us; speedup vs baseline: 1.0515x; 1.0515x over previous
//
#include <hip/hip_runtime.h>
#include <math.h>

#define T_LEN 512
#define AGT __HIP_MEMORY_SCOPE_AGENT
#define SPIN_MAX 65536   // hang-proofing: legit skew <=~10us; this is ~15-30ms
typedef unsigned long long u64;

// LDS-only barrier (SYNC2/SYNC4/SYNC6): drain lgkmcnt (all LDS handoffs) but
// let publish-store / hidden-store acks ride across the barrier -- they drain
// asynchronously under the subsequent poll RTs / next-step compute.
// rule #18: sched_barrier(0) pins ordering after the inline-asm wait.
#define SYNCL() do { \
    asm volatile("s_waitcnt lgkmcnt(0)" ::: "memory"); \
    __builtin_amdgcn_s_barrier(); \
    __builtin_amdgcn_sched_barrier(0); \
} while (0)

// ---------------- workspace layout (bytes) ----------------
// 0x0100 : u64 nullw[5]  stride 32 u64 (256 B)   tagged (tag<<32|bits) null_attn
// 0x0800 : u64 kcg[2][5][32]   (par, mech, DC)   tagged kc (selected variant)
// 0x1800 : u64 vcg[2][5][128]  tagged vc (selected variant)
// 0x4000 : float keys[512*6*64]
// 0x4000+0xC0000 : float vals[512*6*64]
// 0x4000+2*0xC0000 : float hidden[512*640]

__device__ __forceinline__ float tanh_f(float x) {
    const float e = __expf(2.f * x);
    return 1.f - 2.f / (e + 1.f);
}

// ============ kernel 1: key/value projections (parallel) ============
__global__ __launch_bounds__(128) void precompute_kv(
    const float* __restrict__ bert, const int* __restrict__ uidx, const int* __restrict__ pidx,
    const float* __restrict__ disg, const float* __restrict__ udisg,
    const float* __restrict__ utab, const float* __restrict__ ptab,
    const float* __restrict__ Wk0, const float* __restrict__ Wv0,
    const float* __restrict__ Wk1, const float* __restrict__ Wv1,
    const float* __restrict__ Wk2, const float* __restrict__ Wv2,
    const float* __restrict__ Wk3, const float* __restrict__ Wv3,
    const float* __restrict__ Wk4, const float* __restrict__ Wv4,
    float* __restrict__ keys, float* __restrict__ vals)
{
    __shared__ float x[768 + 50 + 20 + 2 + 2];
    const int t = blockIdx.x, tid = threadIdx.x;
    for (int i = tid; i < 768; i += 128) x[i] = bert[t * 768 + i];
    const int u = uidx[t], p = pidx[t];
    for (int i = tid; i < 50; i += 128) x[768 + i] = utab[u * 50 + i];
    for (int i = tid; i < 20; i += 128) x[818 + i] = ptab[p * 20 + i];
    if (tid < 2) x[838 + tid] = disg[t * 2 + tid];
    if (tid >= 2 && tid < 4) x[840 + (tid - 2)] = udisg[t * 2 + (tid - 2)];
    __syncthreads();
    const int j = tid & 63, isv = tid >> 6;
    float* outb = (isv ? vals : keys) + t * 384;
    {   const float* W = isv ? Wv0 : Wk0; float a = 0.f;
        for (int i = 0; i < 768; ++i) a += x[i] * W[i * 64 + j];
        outb[0 * 64 + j] = a; }
    {   const float* W = isv ? Wv1 : Wk1; float a = 0.f;
        for (int i = 0; i < 50; ++i) a += x[768 + i] * W[i * 64 + j];
        outb[1 * 64 + j] = a; }
    {   const float* W = isv ? Wv2 : Wk2; float a = 0.f;
        for (int i = 0; i < 20; ++i) a += x[818 + i] * W[i * 64 + j];
        outb[2 * 64 + j] = a; }
    {   const float* W = isv ? Wv3 : Wk3;
        outb[3 * 64 + j] = x[838] * W[j] + x[839] * W[64 + j]; }
    {   const float* W = isv ? Wv4 : Wk4;
        outb[4 * 64 + j] = x[840] * W[j] + x[841] * W[64 + j]; }
    outb[5 * 64 + j] = 0.f;   // null key/value row
}

// ============ kernel 2: the sequential RIM scan ============
// EXACT round-6 anchor (3092 us: R2 schedule, SYNCL at SYNC2/SYNC4, polls at
// natural positions -- NO issue-early, per round-7 lesson: phase-adjacent
// issue-early quantizes to 2 RTs). ONLY change vs R6: SYNC6 is LDS-only,
// so the hidden[] store acks (~1300cy, consumed only by cls_kernel after
// kernel end) ride instead of stalling all 8 waves every step.
//  S0: w0-3 q-partials
//  S1: w0 attn+softmax+inp -> publish tagged null (u64: tag|bits) immediately
//  S2: gates (reg weights) + LSTM via quad shuffles -> shn;
//      then lanes 0-4 poll remote tagged nulls (flight hidden under gates)
//  S3: selection known -> SINGLE-variant ctx matvecs from h1=sel?shn:sh:
//      w0 qc | w1 kc+pub | w2-5 vc+pub | w6-7 kv prefetch
//  S5: poll remote tagged kc/vc directly (addresses known; one RT) + ctx logits
//  S6: ctx softmax + h2 + state/hidden store
// Transport: agent-scope relaxed u64 atomics (tag travels with data).
// All spins bounded (SPIN_MAX): visibility failure -> wrong answer, not hang.

#define SMEM_FLOATS 35216

__global__ void __attribute__((amdgpu_flat_work_group_size(512, 512), amdgpu_waves_per_eu(2, 2)))
rim_scan(
    const float* __restrict__ Wq, const float* __restrict__ Wih, const float* __restrict__ Whh,
    const float* __restrict__ b_lstm, const float* __restrict__ Wqc, const float* __restrict__ Wkc,
    const float* __restrict__ Wvc,
    const float* __restrict__ keys, const float* __restrict__ vals,
    float* __restrict__ hidden,
    u64* __restrict__ nullw, u64* __restrict__ kcg, u64* __restrict__ vcg)
{
    if (blockIdx.x & 7) return;                 // XCD-pinning dummies
    const int mech = blockIdx.x >> 3;

    extern __shared__ float sm[];
    float* swq  = sm;            // 8192  Wq_T  [64 out][128 K] swizzled
    float* swqc = sm + 8192;     // 4096  Wqc_T [32][128]
    float* swkc = sm + 12288;    // 4096  Wkc_T [32][128]
    float* swvc = sm + 16384;    // 16384 Wvc_T [128][128]
    float* skey = sm + 32768;    // 2*384 key double-buffer
    float* sval = sm + 33536;    // 2*384 val double-buffer
    float* sqp  = sm + 34304;    // 256   q partials (4 segs x 64)
    float* sh   = sm + 34560;    // 128   h state
    float* shn  = sm + 34688;    // 128   h_new candidate
    float* sop  = sm + 34816;    // 192   gate operand: [inp(64) | h(128)]
    float* qcl  = sm + 35008;    // 32    qc (selected variant)
    float* kcl  = sm + 35040;    // 32    kc
    float* vcl  = sm + 35072;    // 128   vc
    float* slog = sm + 35200;    // 8     ctx logits
    float* snull= sm + 35208;    // 8

    const int tid = threadIdx.x;
    const int lane = tid & 63, wv = tid >> 6;

    // ---- stage transposed+swizzled weights into LDS
    for (int idx = tid; idx < 8192; idx += 512) {
        const int i = idx >> 6, j = idx & 63;
        swq[j * 128 + ((((i >> 2) ^ (j & 7)) << 2) | (i & 3))] = Wq[mech * 8192 + idx];
    }
    for (int idx = tid; idx < 4096; idx += 512) {
        const int i = idx >> 5, c = idx & 31;
        const int pos = c * 128 + ((((i >> 2) ^ (c & 7)) << 2) | (i & 3));
        swqc[pos] = Wqc[mech * 4096 + idx];
        swkc[pos] = Wkc[mech * 4096 + idx];
    }
    for (int idx = tid; idx < 16384; idx += 512) {
        const int i = idx >> 7, o = idx & 127;
        swvc[o * 128 + ((((i >> 2) ^ (o & 7)) << 2) | (i & 3))] = Wvc[mech * 16384 + idx];
    }
    if (tid < 384) { skey[tid] = keys[tid]; sval[tid] = vals[tid]; }  // prime t=0
    if (tid < 192) sop[tid] = 0.f;
    if (tid < 128) { sh[tid] = 0.f; shn[tid] = 0.f; }

    // ---- gate weights in registers. quad j covers cell j's 4 gates:
    // pair even -> (i_j, g_j), pair odd -> (f_j, o_j); s = K-half.
    const int pair = tid >> 1, s = tid & 1;
    const int o0 = (pair >> 1) + (pair & 1) * 128;   // i_j or f_j
    const int o1 = o0 + 256;                          // g_j or o_j
    float wA[96], wB[96];
    if (s == 0) {
        #pragma unroll
        for (int k = 0; k < 64; ++k) {
            wA[k] = Wih[mech * 32768 + k * 512 + o0];
            wB[k] = Wih[mech * 32768 + k * 512 + o1];
        }
        #pragma unroll
        for (int k = 0; k < 32; ++k) {
            wA[64 + k] = Whh[mech * 65536 + k * 512 + o0];
            wB[64 + k] = Whh[mech * 65536 + k * 512 + o1];
        }
    } else {
        #pragma unroll
        for (int k = 0; k < 96; ++k) {
            wA[k] = Whh[mech * 65536 + (32 + k) * 512 + o0];
            wB[k] = Whh[mech * 65536 + (32 + k) * 512 + o1];
        }
    }
    const float b0v = (s == 0) ? b_lstm[mech * 512 + o0] : 0.f;
    const float b1v = (s == 0) ? b_lstm[mech * 512 + o1] : 0.f;
    float c_reg = 0.f, cn = 0.f;
    __syncthreads();

    #pragma unroll 1
    for (int t = 0; t < T_LEN; ++t) {
        const int par = t & 1;
        const unsigned tgt = (unsigned)(t + 1);
        const float* kb = skey + par * 384;
        const float* vb = sval + par * 384;

        // one-wave 32-out matvec (2 lanes/out), optional tagged publish
        auto qk32 = [&](const float* Wl, const float* hsrc, float* dstL, u64* gbase) {
            const int out = lane >> 1, s2 = lane & 1, rx = out & 7;
            const float* wrow = Wl + out * 128;
            const float4* h4 = (const float4*)(hsrc + s2 * 64);
            float p = 0.f;
            #pragma unroll
            for (int j = 0; j < 16; ++j) {
                const float4 w = *(const float4*)(wrow + (((s2 * 16 + j) ^ rx) << 2));
                const float4 hv = h4[j];
                p += w.x * hv.x + w.y * hv.y + w.z * hv.z + w.w * hv.w;
            }
            p += __shfl_xor(p, 1);
            if (s2 == 0) {
                dstL[out] = p;
                if (gbase)
                    __hip_atomic_store(gbase + out,
                                       ((u64)tgt << 32) | (u64)__float_as_uint(p),
                                       __ATOMIC_RELAXED, AGT);
            }
        };
        // four-wave 128-out vc matvec (2 lanes/out), tagged publish
        auto vc128 = [&](const float* hsrc, int wbase) {
            const int out = (wv - wbase) * 32 + (lane >> 1), s2 = lane & 1, rx = out & 7;
            const float* wrow = swvc + out * 128;
            const float4* h4 = (const float4*)(hsrc + s2 * 64);
            float p = 0.f;
            #pragma unroll
            for (int j = 0; j < 16; ++j) {
                const float4 w = *(const float4*)(wrow + (((s2 * 16 + j) ^ rx) << 2));
                const float4 hv = h4[j];
                p += w.x * hv.x + w.y * hv.y + w.z * hv.z + w.w * hv.w;
            }
            p += __shfl_xor(p, 1);
            if (s2 == 0) {
                vcl[out] = p;
                __hip_atomic_store(vcg + (((par * 5 + mech) << 7) + out),
                                   ((u64)tgt << 32) | (u64)__float_as_uint(p),
                                   __ATOMIC_RELAXED, AGT);
            }
        };

        // ================= S0: q partials =================
        if (wv < 4) {
            const int out = lane, rx = out & 7;
            const float* wrow = swq + out * 128;
            const float4* h4 = (const float4*)(sh + wv * 32);
            float acc = 0.f;
            #pragma unroll
            for (int j = 0; j < 8; ++j) {
                const float4 w = *(const float4*)(wrow + (((wv * 8 + j) ^ rx) << 2));
                const float4 hv = h4[j];
                acc += w.x * hv.x + w.y * hv.y + w.z * hv.z + w.w * hv.w;
            }
            sqp[wv * 64 + out] = acc;
        }
        __syncthreads();   // SYNC1 (full)

        // ================= S1: attention + tagged null publish =================
        if (wv == 0) {
            const float q = sqp[lane] + sqp[64 + lane] + sqp[128 + lane] + sqp[192 + lane];
            float l[6];
            #pragma unroll
            for (int k = 0; k < 6; ++k) {
                float p = q * kb[k * 64 + lane];
                p += __shfl_down(p, 32); p += __shfl_down(p, 16); p += __shfl_down(p, 8);
                p += __shfl_down(p, 4);  p += __shfl_down(p, 2);  p += __shfl_down(p, 1);
                l[k] = __shfl(p, 0) * 0.125f;
            }
            const float mx = fmaxf(fmaxf(fmaxf(l[0], l[1]), fmaxf(l[2], l[3])), fmaxf(l[4], l[5]));
            const float e0 = __expf(l[0] - mx), e1 = __expf(l[1] - mx), e2 = __expf(l[2] - mx);
            const float e3 = __expf(l[3] - mx), e4 = __expf(l[4] - mx), e5 = __expf(l[5] - mx);
            const float inv = 1.f / (e0 + e1 + e2 + e3 + e4 + e5);
            sop[lane] = (e0 * vb[lane] + e1 * vb[64 + lane] + e2 * vb[128 + lane]
                       + e3 * vb[192 + lane] + e4 * vb[256 + lane] + e5 * vb[320 + lane]) * inv;
            if (lane == 0) {
                const float nv = e5 * inv;
                snull[mech] = nv;
                __hip_atomic_store(nullw + (mech << 5),
                                   ((u64)tgt << 32) | (u64)__float_as_uint(nv),
                                   __ATOMIC_RELAXED, AGT);
            }
        }
        SYNCL();   // SYNC2 (LDS-only: null-publish ack rides into S2)

        // ================= S2: gates + LSTM, then null polls =================
        {
            const float4* op = (const float4*)(sop + s * 96);
            float p0 = b0v, p1 = b1v;
            #pragma unroll
            for (int q = 0; q < 24; ++q) {
                const float4 v = op[q];
                p0 += v.x * wA[4 * q] + v.y * wA[4 * q + 1] + v.z * wA[4 * q + 2] + v.w * wA[4 * q + 3];
                p1 += v.x * wB[4 * q] + v.y * wB[4 * q + 1] + v.z * wB[4 * q + 2] + v.w * wB[4 * q + 3];
            }
            const float r0 = p0 + __shfl_xor(p0, 1);
            const float r1 = p1 + __shfl_xor(p1, 1);
            const float t0 = __shfl_xor(r0, 2);
            const float t1 = __shfl_xor(r1, 2);
            const bool even = ((pair & 1) == 0);
            const float gi = even ? r0 : t0;
            const float gg = even ? r1 : t1;
            const float gf = even ? t0 : r0;
            const float go = even ? t1 : r1;
            const float si = 1.f / (1.f + __expf(-gi));
            const float sf = 1.f / (1.f + __expf(-gf));
            const float so = 1.f / (1.f + __expf(-go));
            cn = sf * c_reg + si * tanh_f(gg);
            const float hn = so * tanh_f(cn);
            if ((tid & 3) == 0) shn[tid >> 2] = hn;
        }
        if (tid < 5 && tid != mech) {
            const u64* np = nullw + (tid << 5);
            u64 w = __hip_atomic_load(np, __ATOMIC_RELAXED, AGT);
            int spin = 0;
            while ((unsigned)(w >> 32) < tgt && ++spin < SPIN_MAX)
                w = __hip_atomic_load(np, __ATOMIC_RELAXED, AGT);
            snull[tid] = __uint_as_float((unsigned)w);
        }
        __syncthreads();   // SYNC3 (full)

        // ================= S3: selection + single-variant matvecs =================
        int selfAct;
        {
            const float myn = snull[mech]; int r = 0;
            #pragma unroll
            for (int mm = 0; mm < 5; ++mm) {
                const float o = snull[mm];
                r += (o < myn || (o == myn && mm < mech)) ? 1 : 0;
            }
            selfAct = (r < 3) ? 1 : 0;
        }
        c_reg = selfAct ? cn : c_reg;
        {
            const float* hsrc = selfAct ? shn : sh;
            if (wv == 0)      qk32(swqc, hsrc, qcl, (u64*)0);
            else if (wv == 1) qk32(swkc, hsrc, kcl, kcg + ((par * 5 + mech) << 5));
            else if (wv >= 2 && wv <= 5) vc128(hsrc, 2);
            else if (wv == 6) {
                const int tn = (t < T_LEN - 1) ? t + 1 : t;
                const float4* kn = (const float4*)(keys + tn * 384);
                float4* kd = (float4*)(skey + ((t + 1) & 1) * 384);
                kd[lane] = kn[lane];
                if (lane < 32) kd[64 + lane] = kn[64 + lane];
            } else {
                const int tn = (t < T_LEN - 1) ? t + 1 : t;
                const float4* vn = (const float4*)(vals + tn * 384);
                float4* vd = (float4*)(sval + ((t + 1) & 1) * 384);
                vd[lane] = vn[lane];
                if (lane < 32) vd[64 + lane] = vn[64 + lane];
            }
        }
        SYNCL();   // SYNC4 (LDS-only: kc/vc publish acks drain under S5's poll RT)

        // ================= S5: tagged kc/vc polls + ctx logits =================
        float v0 = 0.f, v1 = 0.f, v2 = 0.f, v3 = 0.f, v4 = 0.f;
        if (wv >= 3 && lane < 32) {
            const int m2 = wv - 3;
            float kcv;
            if (m2 == mech) kcv = kcl[lane];
            else {
                const u64* kp = kcg + (((par * 5 + m2) << 5) + lane);
                u64 w = __hip_atomic_load(kp, __ATOMIC_RELAXED, AGT);
                int spin = 0;
                while ((unsigned)(w >> 32) < tgt && ++spin < SPIN_MAX)
                    w = __hip_atomic_load(kp, __ATOMIC_RELAXED, AGT);
                kcv = __uint_as_float((unsigned)w);
            }
            float p = qcl[lane] * kcv;
            p += __shfl_down(p, 16); p += __shfl_down(p, 8); p += __shfl_down(p, 4);
            p += __shfl_down(p, 2);  p += __shfl_down(p, 1);
            if (lane == 0) slog[m2] = p * 0.17677669529663687f;
        }
        if (tid < 128) {
            const u64* b = vcg + tid;
            u64 a0 = 0, a1 = 0, a2 = 0, a3 = 0, a4 = 0;
            if (mech != 0) a0 = __hip_atomic_load(b + ((par * 5 + 0) << 7), __ATOMIC_RELAXED, AGT);
            if (mech != 1) a1 = __hip_atomic_load(b + ((par * 5 + 1) << 7), __ATOMIC_RELAXED, AGT);
            if (mech != 2) a2 = __hip_atomic_load(b + ((par * 5 + 2) << 7), __ATOMIC_RELAXED, AGT);
            if (mech != 3) a3 = __hip_atomic_load(b + ((par * 5 + 3) << 7), __ATOMIC_RELAXED, AGT);
            if (mech != 4) a4 = __hip_atomic_load(b + ((par * 5 + 4) << 7), __ATOMIC_RELAXED, AGT);
            int spin = 0;
            if (mech != 0) while ((unsigned)(a0 >> 32) < tgt && ++spin < SPIN_MAX)
                a0 = __hip_atomic_load(b + ((par * 5 + 0) << 7), __ATOMIC_RELAXED, AGT);
            if (mech != 1) while ((unsigned)(a1 >> 32) < tgt && ++spin < SPIN_MAX)
                a1 = __hip_atomic_load(b + ((par * 5 + 1) << 7), __ATOMIC_RELAXED, AGT);
            if (mech != 2) while ((unsigned)(a2 >> 32) < tgt && ++spin < SPIN_MAX)
                a2 = __hip_atomic_load(b + ((par * 5 + 2) << 7), __ATOMIC_RELAXED, AGT);
            if (mech != 3) while ((unsigned)(a3 >> 32) < tgt && ++spin < SPIN_MAX)
                a3 = __hip_atomic_load(b + ((par * 5 + 3) << 7), __ATOMIC_RELAXED, AGT);
            if (mech != 4) while ((unsigned)(a4 >> 32) < tgt && ++spin < SPIN_MAX)
                a4 = __hip_atomic_load(b + ((par * 5 + 4) << 7), __ATOMIC_RELAXED, AGT);
            v0 = (mech == 0) ? vcl[tid] : __uint_as_float((unsigned)a0);
            v1 = (mech == 1) ? vcl[tid] : __uint_as_float((unsigned)a1);
            v2 = (mech == 2) ? vcl[tid] : __uint_as_float((unsigned)a2);
            v3 = (mech == 3) ? vcl[tid] : __uint_as_float((unsigned)a3);
            v4 = (mech == 4) ? vcl[tid] : __uint_as_float((unsigned)a4);
        }
        __syncthreads();   // SYNC5 (full)

        // ================= S6: ctx softmax + h2 + store =================
        if (tid < 128) {
            const float l0 = slog[0], l1 = slog[1], l2 = slog[2], l3 = slog[3], l4 = slog[4];
            const float mx = fmaxf(fmaxf(fmaxf(l0, l1), fmaxf(l2, l3)), l4);
            const float e0 = __expf(l0 - mx), e1 = __expf(l1 - mx), e2 = __expf(l2 - mx);
            const float e3 = __expf(l3 - mx), e4 = __expf(l4 - mx);
            const float inv = 1.f / (e0 + e1 + e2 + e3 + e4);
            float hv = selfAct ? shn[tid] : sh[tid];
            if (selfAct) hv += (e0 * v0 + e1 * v1 + e2 * v2 + e3 * v3 + e4 * v4) * inv;
            sh[tid] = hv;
            sop[64 + tid] = hv;
            hidden[t * 640 + mech * 128 + tid] = hv;   // ack rides (reader is cls_kernel)
        }
        SYNCL();   // SYNC6 (LDS-only: hidden-store acks ride into next step)
    }
}

// ============ kernel 3: classifier ============
__global__ __launch_bounds__(256) void cls_kernel(
    const float* __restrict__ hidden, const float* __restrict__ Wcls,
    const float* __restrict__ bcls, float* __restrict__ out)
{
    const int t = blockIdx.x * 256 + threadIdx.x;
    if (t >= T_LEN) return;
    float a0 = bcls[0], a1 = bcls[1];
    for (int d = 0; d < 640; ++d) {
        const float h = hidden[t * 640 + d];
        a0 += h * Wcls[d * 2 + 0];
        a1 += h * Wcls[d * 2 + 1];
    }
    out[t * 2 + 0] = a0;
    out[t * 2 + 1] = a1;
}

extern "C" void kernel_launch(void* const* d_in, const int* in_sizes, int n_in,
                              void* d_out, int out_size, void* d_ws, size_t ws_size,
                              hipStream_t stream)
{
    (void)in_sizes; (void)n_in; (void)out_size; (void)ws_size;
    const float* bert  = (const float*)d_in[0];
    const int*   uidx  = (const int*)d_in[1];
    const int*   pidx  = (const int*)d_in[2];
    const float* disg  = (const float*)d_in[3];
    const float* udisg = (const float*)d_in[4];
    const float* utab  = (const float*)d_in[5];
    const float* ptab  = (const float*)d_in[6];
    const float* Wk0 = (const float*)d_in[7],  *Wv0 = (const float*)d_in[8];
    const float* Wk1 = (const float*)d_in[9],  *Wv1 = (const float*)d_in[10];
    const float* Wk2 = (const float*)d_in[11], *Wv2 = (const float*)d_in[12];
    const float* Wk3 = (const float*)d_in[13], *Wv3 = (const float*)d_in[14];
    const float* Wk4 = (const float*)d_in[15], *Wv4 = (const float*)d_in[16];
    const float* Wq   = (const float*)d_in[17];
    const float* Wih  = (const float*)d_in[18];
    const float* Whh  = (const float*)d_in[19];
    const float* bl   = (const float*)d_in[20];
    const float* Wqc  = (const float*)d_in[21];
    const float* Wkc  = (const float*)d_in[22];
    const float* Wvc  = (const float*)d_in[23];
    const float* Wcls = (const float*)d_in[24];
    const float* bcls = (const float*)d_in[25];

    char* ws = (char*)d_ws;
    u64* nullw = (u64*)(ws + 0x100);    // stride 32 u64 = 256 B per mech
    u64* kcg   = (u64*)(ws + 0x800);
    u64* vcg   = (u64*)(ws + 0x1800);
    float* keys   = (float*)(ws + 0x4000);
    float* vals   = (float*)(ws + 0x4000 + 786432);
    float* hidden = (float*)(ws + 0x4000 + 2 * 786432);

    hipMemsetAsync(d_ws, 0, 0x4000, stream);   // zero all mailbox tags

    hipLaunchKernelGGL(precompute_kv, dim3(T_LEN), dim3(128), 0, stream,
        bert, uidx, pidx, disg, udisg, utab, ptab,
        Wk0, Wv0, Wk1, Wv1, Wk2, Wv2, Wk3, Wv3, Wk4, Wv4, keys, vals);

    const int smem_bytes = SMEM_FLOATS * 4;   // 140864 B < 160 KiB
    (void)hipFuncSetAttribute((const void*)rim_scan,
                              hipFuncAttributeMaxDynamicSharedMemorySize, smem_bytes);
    hipLaunchKernelGGL(rim_scan, dim3(33), dim3(512), smem_bytes, stream,
        Wq, Wih, Whh, bl, Wqc, Wkc, Wvc, keys, vals, hidden, nullw, kcg, vcg);

    hipLaunchKernelGGL(cls_kernel, dim3(2), dim3(256), 0, stream,
        hidden, Wcls, bcls, (float*)d_out);
}